// Round 1
// baseline (2147.302 us; speedup 1.0000x reference)
//
#include <hip/hip_runtime.h>

#define N_PTS 200000
#define GRIDL 192
#define CAP 8192            // per-tap bin capacity (mean ~5560, 34 sigma margin)
#define NREG 1728           // 12^3 regions of 16^3 cells
#define RCAP 256            // per-region point capacity (mean ~116, 13 sigma)

// ---- workspace layout (bytes), all 16-aligned ----
#define VOL_OFF   0ull
#define VOL_BYTES (192ull*192ull*192ull*4ull)   // 28,311,552
#define BINS_OFF  28311552ull                   // 125*8192*8 = 8,192,000
#define BCNT_OFF  36503552ull                   // 512
#define RCNT_OFF  36504064ull                   // 1728*4 = 6,912
#define PLIST_OFF 36510976ull                   // 1728*256*8 = 3,538,944
#define WBUF_OFF  40049920ull                   // 125*2304*4 = 1,152,000
#define VTAB_OFF  41201920ull                   // 125*16 = 2,000
#define A0_OFF    41203920ull                   // 4,096
#define A1_OFF    41208016ull                   // 1,024

// ============================================================
// Kernel 1: build scaled structured weights + fused sc matrices
// w[p,q] = sum_r EMB[p,r]*weight[r,q] / 125, scaled per block:
//   W1,W2,W3 *= ALPHA ; W4 *= ALPHA/sqrt(3) = 1/12
// A0 = w_sc0/sqrt(32) + W1[62] (=0), A1 = w_sc1/4 + W3[62] (=0)
// ============================================================
__global__ void prep_kernel(const float* __restrict__ wt, const float* __restrict__ wsc0,
                            const float* __restrict__ wsc1, float* __restrict__ wbuf,
                            float* __restrict__ vtab, float* __restrict__ A0,
                            float* __restrict__ A1) {
    int p = blockIdx.x;
    int dx = p / 25 - 2, dy = (p / 5) % 5 - 2, dz = p % 5 - 2;
    double d = sqrt((double)(dx*dx + dy*dy + dz*dz));
    const double step = 2.5 / 9.0;
    const double cst = 1.14136 * exp(2.0);
    float emb[8];
#pragma unroll
    for (int r = 0; r < 8; r++) {
        double t = (d - (double)(r + 1) * step) / step;
        double tt = t * t;
        emb[r] = (tt < 1.0) ? (float)(cst * exp(-2.0 / (1.0 - tt))) : 0.0f;
    }
    if (threadIdx.x == 0) {
        float inv = (d > 0.0) ? (float)(sqrt(3.0) / d) : 0.0f;
        vtab[p*4+0] = dx * inv; vtab[p*4+1] = dy * inv;
        vtab[p*4+2] = dz * inv; vtab[p*4+3] = 0.0f;
    }
    const float ALPHA = 0.14433756729740643f;   // 1/sqrt(48)
    for (int q = threadIdx.x; q < 2304; q += blockDim.x) {
        float acc = 0.0f;
#pragma unroll
        for (int r = 0; r < 8; r++) acc = fmaf(emb[r], wt[r*2304 + q], acc);
        acc *= (1.0f / 125.0f);
        float val = acc * ((q < 1792) ? ALPHA : (1.0f / 12.0f));
        wbuf[p*2304 + q] = val;
        if (p == 62) {  // center: val==0 (EMB(0)=0) but keep the add for exactness
            if (q < 1024)                 A0[q]        = wsc0[q] * 0.17677669529663687f + val;
            else if (q >= 1536 && q < 1792) A1[q-1536] = wsc1[q-1536] * 0.25f + val;
        }
    }
}

// ============================================================
// Kernel 2: scatter points into volume + 16^3 region lists
// ============================================================
__global__ void scatter_kernel(const int* __restrict__ coords, int* __restrict__ vol,
                               int* __restrict__ rcnt, int2* __restrict__ plist) {
    int n = blockIdx.x * blockDim.x + threadIdx.x;
    if (n >= N_PTS) return;
    int x = coords[n*3], y = coords[n*3+1], z = coords[n*3+2];
    vol[(x * GRIDL + y) * GRIDL + z] = n;
    int r = (x >> 4) * 144 + (y >> 4) * 12 + (z >> 4);
    int j = atomicAdd(&rcnt[r], 1);
    if (j < RCAP) plist[r * RCAP + j] = make_int2(n, (x << 16) | (y << 8) | z);
}

// ============================================================
// Kernel 3: enumerate hits per live tap into per-tap bins.
// One block per spatial region -> probes stay in a ~32KB window (L1/L2).
// Tap loop is compile-time unrolled and wave-uniform -> ballot aggregation,
// one bin atomic per wave per tap. Taps with ||off||^2 outside [1,6] have
// identically-zero kernels and are skipped.
// ============================================================
__global__ __launch_bounds__(128) void enum_kernel(const int* __restrict__ vol,
        const int* __restrict__ rcnt, const int2* __restrict__ plist,
        int* __restrict__ bcnt, int2* __restrict__ bins) {
    int r = blockIdx.x;
    int cnt = min(rcnt[r], RCAP);
    int lane = threadIdx.x & 63;
    for (int base = 0; base < cnt; base += 128) {
        int idx = base + threadIdx.x;
        bool act = idx < cnt;
        int n = -1, x = 0, y = 0, z = 0;
        if (act) {
            int2 e = plist[r * RCAP + idx];
            n = e.x; x = e.y >> 16; y = (e.y >> 8) & 255; z = e.y & 255;
        }
#pragma unroll
        for (int a = -2; a <= 2; a++)
#pragma unroll
        for (int b = -2; b <= 2; b++)
#pragma unroll
        for (int c = -2; c <= 2; c++) {
            int sq = a*a + b*b + c*c;
            if (sq < 1 || sq > 6) continue;      // zero radial embedding -> K==0
            int p = (a + 2) * 25 + (b + 2) * 5 + (c + 2);
            int cx = x + a, cy = y + b, cz = z + c;
            bool valid = act && ((unsigned)cx < 192u) && ((unsigned)cy < 192u) &&
                         ((unsigned)cz < 192u);
            int nb = -1;
            if (valid) nb = vol[(cx * GRIDL + cy) * GRIDL + cz];
            bool hit = nb >= 0;
            unsigned long long m = __ballot(hit);
            if (m) {
                int prefix = __popcll(m & ((1ull << lane) - 1ull));
                int leader = __ffsll((unsigned long long)m) - 1;
                int bb = 0;
                if (lane == leader) bb = atomicAdd(&bcnt[p], (int)__popcll(m));
                bb = __shfl(bb, leader, 64);
                if (hit) {
                    int slot = bb + prefix;
                    if (slot < CAP) bins[p * CAP + slot] = make_int2(n, nb);
                }
            }
        }
    }
}

// ============================================================
// Kernel 4: out[n] = sc(feats[n])  (self kernel K[62]==0 folded in A0/A1)
// A0 (32x32) and A1 (16x16) in LDS, wave-uniform broadcast reads.
// Fully initializes d_out.
// ============================================================
__global__ __launch_bounds__(256) void sc_self_kernel(const float* __restrict__ feats,
        const float* __restrict__ A0, const float* __restrict__ A1,
        float* __restrict__ out) {
    __shared__ __align__(16) float sA0[1024];
    __shared__ __align__(16) float sA1[256];
    for (int i = threadIdx.x; i < 1024; i += 256) sA0[i] = A0[i];
    if (threadIdx.x < 256) sA1[threadIdx.x] = A1[threadIdx.x];
    __syncthreads();
    int n = blockIdx.x * 256 + threadIdx.x;
    if (n >= N_PTS) return;
    const float4* fr = (const float4*)(feats + (size_t)n * 80);
    float4* orow = (float4*)(out + (size_t)n * 80);
    // ---- out0 = f0 @ A0 ----
    float f0[32];
#pragma unroll
    for (int j = 0; j < 8; j++) {
        float4 t = fr[j];
        f0[4*j] = t.x; f0[4*j+1] = t.y; f0[4*j+2] = t.z; f0[4*j+3] = t.w;
    }
    float a0[32];
#pragma unroll
    for (int k = 0; k < 32; k++) a0[k] = 0.0f;
#pragma unroll
    for (int i = 0; i < 32; i++) {
        float fv = f0[i];
#pragma unroll
        for (int k4 = 0; k4 < 8; k4++) {
            float4 w = ((const float4*)sA0)[i*8 + k4];
            a0[4*k4]   = fmaf(fv, w.x, a0[4*k4]);
            a0[4*k4+1] = fmaf(fv, w.y, a0[4*k4+1]);
            a0[4*k4+2] = fmaf(fv, w.z, a0[4*k4+2]);
            a0[4*k4+3] = fmaf(fv, w.w, a0[4*k4+3]);
        }
    }
#pragma unroll
    for (int j = 0; j < 8; j++) orow[j] = make_float4(a0[4*j], a0[4*j+1], a0[4*j+2], a0[4*j+3]);
    // ---- out1[3k+m] = sum_i f1[3i+m] * A1[i][k] ----
    float f1[48];
#pragma unroll
    for (int j = 0; j < 12; j++) {
        float4 t = fr[8 + j];
        f1[4*j] = t.x; f1[4*j+1] = t.y; f1[4*j+2] = t.z; f1[4*j+3] = t.w;
    }
    float a1[48];
#pragma unroll
    for (int k = 0; k < 48; k++) a1[k] = 0.0f;
#pragma unroll
    for (int i = 0; i < 16; i++) {
        float fm0 = f1[3*i], fm1 = f1[3*i+1], fm2 = f1[3*i+2];
#pragma unroll
        for (int k4 = 0; k4 < 4; k4++) {
            float4 w = ((const float4*)sA1)[i*4 + k4];
            const float* wp = (const float*)&w;
#pragma unroll
            for (int kk = 0; kk < 4; kk++) {
                int k = 4*k4 + kk;
                a1[3*k]   = fmaf(fm0, wp[kk], a1[3*k]);
                a1[3*k+1] = fmaf(fm1, wp[kk], a1[3*k+1]);
                a1[3*k+2] = fmaf(fm2, wp[kk], a1[3*k+2]);
            }
        }
    }
#pragma unroll
    for (int j = 0; j < 12; j++) orow[8+j] = make_float4(a1[4*j], a1[4*j+1], a1[4*j+2], a1[4*j+3]);
}

// ============================================================
// Kernel 5: per-tap bins. Structured weights in LDS (uniform broadcast
// b128 reads), one hit per lane, LDS-staged transpose, row-coalesced
// fp32 atomics into out.
// ============================================================
__global__ __launch_bounds__(128) void bin_kernel(const float* __restrict__ feats,
        const float* __restrict__ wbuf, const float* __restrict__ vtab,
        const int* __restrict__ bcnt, const int2* __restrict__ bins,
        float* __restrict__ out) {
    int p = blockIdx.x >> 4;
    int chunk = blockIdx.x & 15;
    int cnt = min(bcnt[p], CAP);
    int start = chunk * 512;
    if (start >= cnt) return;

    __shared__ __align__(16) float sW[2304];
    __shared__ float sv[4];
    __shared__ float ystage[2][64][81];   // pad 81 (odd): conflict-free both ways
    __shared__ int   nst[2][64];

    for (int i = threadIdx.x; i < 2304; i += 128) sW[i] = wbuf[p*2304 + i];
    if (threadIdx.x < 4) sv[threadIdx.x] = vtab[p*4 + threadIdx.x];
    __syncthreads();

    int wv = threadIdx.x >> 6, lane = threadIdx.x & 63;
    const float4* sW1 = (const float4*)sW;            // [32][8]  (32x32)
    const float4* sW2 = (const float4*)(sW + 1024);   // [32][4]  (32x16)
    const float4* sW3 = (const float4*)(sW + 1536);   // [16][4]  (16x16)
    const float4* sW4 = (const float4*)(sW + 1792);   // [16][8]  (16x32)
    float v0 = sv[0], v1 = sv[1], v2 = sv[2];

    for (int it = 0; it < 4; it++) {
        int h = start + it * 128 + threadIdx.x;
        bool act = h < cnt;
        int n = -1, nb = 0;
        if (act) { int2 e = bins[p*CAP + h]; n = e.x; nb = e.y; }

        const float4* fr = (const float4*)(feats + (size_t)nb * 80);
        float f0[32], f1[48];
#pragma unroll
        for (int j = 0; j < 8; j++) {
            float4 t = fr[j];
            f0[4*j] = t.x; f0[4*j+1] = t.y; f0[4*j+2] = t.z; f0[4*j+3] = t.w;
        }
#pragma unroll
        for (int j = 0; j < 12; j++) {
            float4 t = fr[8 + j];
            f1[4*j] = t.x; f1[4*j+1] = t.y; f1[4*j+2] = t.z; f1[4*j+3] = t.w;
        }
        float g[16];
#pragma unroll
        for (int i = 0; i < 16; i++)
            g[i] = f1[3*i]*v0 + f1[3*i+1]*v1 + f1[3*i+2]*v2;

        // out0 = f0@W1 + g@W4 ; cc = f0@W2
        float a0[32], cc[16];
#pragma unroll
        for (int k = 0; k < 32; k++) a0[k] = 0.0f;
#pragma unroll
        for (int k = 0; k < 16; k++) cc[k] = 0.0f;
#pragma unroll
        for (int i = 0; i < 32; i++) {
            float fv = f0[i];
#pragma unroll
            for (int k4 = 0; k4 < 8; k4++) {
                float4 w = sW1[i*8 + k4];
                a0[4*k4]   = fmaf(fv, w.x, a0[4*k4]);
                a0[4*k4+1] = fmaf(fv, w.y, a0[4*k4+1]);
                a0[4*k4+2] = fmaf(fv, w.z, a0[4*k4+2]);
                a0[4*k4+3] = fmaf(fv, w.w, a0[4*k4+3]);
            }
#pragma unroll
            for (int k4 = 0; k4 < 4; k4++) {
                float4 w = sW2[i*4 + k4];
                cc[4*k4]   = fmaf(fv, w.x, cc[4*k4]);
                cc[4*k4+1] = fmaf(fv, w.y, cc[4*k4+1]);
                cc[4*k4+2] = fmaf(fv, w.z, cc[4*k4+2]);
                cc[4*k4+3] = fmaf(fv, w.w, cc[4*k4+3]);
            }
        }
#pragma unroll
        for (int i = 0; i < 16; i++) {
            float gv = g[i];
#pragma unroll
            for (int k4 = 0; k4 < 8; k4++) {
                float4 w = sW4[i*8 + k4];
                a0[4*k4]   = fmaf(gv, w.x, a0[4*k4]);
                a0[4*k4+1] = fmaf(gv, w.y, a0[4*k4+1]);
                a0[4*k4+2] = fmaf(gv, w.z, a0[4*k4+2]);
                a0[4*k4+3] = fmaf(gv, w.w, a0[4*k4+3]);
            }
        }
#pragma unroll
        for (int k = 0; k < 32; k++) ystage[wv][lane][k] = a0[k];

        // out1[3k+m] = v[m]*cc[k] + sum_i f1[3i+m]*W3[i][k]
        float a1[48];
#pragma unroll
        for (int k = 0; k < 16; k++) {
            a1[3*k] = v0 * cc[k]; a1[3*k+1] = v1 * cc[k]; a1[3*k+2] = v2 * cc[k];
        }
#pragma unroll
        for (int i = 0; i < 16; i++) {
            float fm0 = f1[3*i], fm1 = f1[3*i+1], fm2 = f1[3*i+2];
#pragma unroll
            for (int k4 = 0; k4 < 4; k4++) {
                float4 w = sW3[i*4 + k4];
                const float* wp = (const float*)&w;
#pragma unroll
                for (int kk = 0; kk < 4; kk++) {
                    int k = 4*k4 + kk;
                    a1[3*k]   = fmaf(fm0, wp[kk], a1[3*k]);
                    a1[3*k+1] = fmaf(fm1, wp[kk], a1[3*k+1]);
                    a1[3*k+2] = fmaf(fm2, wp[kk], a1[3*k+2]);
                }
            }
        }
#pragma unroll
        for (int k = 0; k < 48; k++) ystage[wv][lane][32 + k] = a1[k];
        nst[wv][lane] = act ? n : -1;
        __syncthreads();

        // coalesced atomic flush: one output row per inner step
        for (int h2 = 0; h2 < 64; h2++) {
            int nn = nst[wv][h2];          // wave-uniform
            if (nn < 0) continue;
            float* orow = out + (size_t)nn * 80;
            unsafeAtomicAdd(orow + lane, ystage[wv][h2][lane]);
            if (lane < 16) unsafeAtomicAdd(orow + 64 + lane, ystage[wv][h2][64 + lane]);
        }
        __syncthreads();
    }
}

extern "C" void kernel_launch(void* const* d_in, const int* in_sizes, int n_in,
                              void* d_out, int out_size, void* d_ws, size_t ws_size,
                              hipStream_t stream) {
    const float* feats = (const float*)d_in[0];
    const float* wt    = (const float*)d_in[1];
    const float* wsc0  = (const float*)d_in[2];
    const float* wsc1  = (const float*)d_in[3];
    const int*   coords= (const int*)d_in[4];
    float* out = (float*)d_out;
    char* ws = (char*)d_ws;

    int*   vol   = (int*)(ws + VOL_OFF);
    int2*  bins  = (int2*)(ws + BINS_OFF);
    int*   bcnt  = (int*)(ws + BCNT_OFF);
    int*   rcnt  = (int*)(ws + RCNT_OFF);
    int2*  plist = (int2*)(ws + PLIST_OFF);
    float* wbuf  = (float*)(ws + WBUF_OFF);
    float* vtab  = (float*)(ws + VTAB_OFF);
    float* A0    = (float*)(ws + A0_OFF);
    float* A1    = (float*)(ws + A1_OFF);

    hipMemsetAsync(vol, 0xFF, VOL_BYTES, stream);            // -1 everywhere
    hipMemsetAsync(bcnt, 0, 512 + 6912, stream);             // bcnt + rcnt

    prep_kernel<<<125, 256, 0, stream>>>(wt, wsc0, wsc1, wbuf, vtab, A0, A1);
    scatter_kernel<<<(N_PTS + 255) / 256, 256, 0, stream>>>(coords, vol, rcnt, plist);
    enum_kernel<<<NREG, 128, 0, stream>>>(vol, rcnt, plist, bcnt, bins);
    sc_self_kernel<<<(N_PTS + 255) / 256, 256, 0, stream>>>(feats, A0, A1, out);
    bin_kernel<<<125 * 16, 128, 0, stream>>>(feats, wbuf, vtab, bcnt, bins, out);
}

// Round 2
// 471.989 us; speedup vs baseline: 4.5495x; 4.5495x over previous
//
#include <hip/hip_runtime.h>

#define N_PTS 200000
#define GRIDL 192
#define CAP 8192            // per-tap bin capacity (mean ~5651, sigma ~74)
#define NREG 216            // 6^3 regions of 32^3 cells
#define RCAP 1152           // per-region point capacity (mean ~926, sigma ~30)
#define SCAP 96             // per-(block,tap) LDS stage capacity (mean 26.1, sigma 5.1)

// ---- workspace layout (bytes), all 16-aligned ----
#define VOL_OFF   0ull
#define VOL_BYTES (192ull*192ull*192ull*4ull)   // 28,311,552
#define BINS_OFF  28311552ull                   // 125*8192*8 = 8,192,000
#define BCNT_OFF  36503552ull                   // 125*32*4 = 16,000 (128B-padded)
#define RCNT_OFF  36519552ull                   // 216*32*4 = 27,648 (128B-padded)
#define PLIST_OFF 36547200ull                   // 216*1152*8 = 1,990,656
#define WBUF_OFF  38537856ull                   // 125*2304*4 = 1,152,000
#define VTAB_OFF  39689856ull                   // 125*16 = 2,000
#define A0_OFF    39691856ull                   // 4,096
#define A1_OFF    39695952ull                   // 1,024

// 80 live taps (1 <= ||off||^2 <= 6); table of p = (a+2)*25+(b+2)*5+(c+2)
struct TapTable { int p[80]; };
__host__ __device__ constexpr TapTable make_taps() {
    TapTable tt{}; int t = 0;
    for (int a = -2; a <= 2; a++)
        for (int b = -2; b <= 2; b++)
            for (int c = -2; c <= 2; c++) {
                int sq = a*a + b*b + c*c;
                if (sq >= 1 && sq <= 6) tt.p[t++] = (a+2)*25 + (b+2)*5 + (c+2);
            }
    return tt;
}
__device__ const TapTable TAPS = make_taps();

// ============================================================
// Kernel 1: build scaled structured weights + fused sc matrices
// ============================================================
__global__ void prep_kernel(const float* __restrict__ wt, const float* __restrict__ wsc0,
                            const float* __restrict__ wsc1, float* __restrict__ wbuf,
                            float* __restrict__ vtab, float* __restrict__ A0,
                            float* __restrict__ A1) {
    int p = blockIdx.x;
    int dx = p / 25 - 2, dy = (p / 5) % 5 - 2, dz = p % 5 - 2;
    double d = sqrt((double)(dx*dx + dy*dy + dz*dz));
    const double step = 2.5 / 9.0;
    const double cst = 1.14136 * exp(2.0);
    float emb[8];
#pragma unroll
    for (int r = 0; r < 8; r++) {
        double t = (d - (double)(r + 1) * step) / step;
        double tt = t * t;
        emb[r] = (tt < 1.0) ? (float)(cst * exp(-2.0 / (1.0 - tt))) : 0.0f;
    }
    if (threadIdx.x == 0) {
        float inv = (d > 0.0) ? (float)(sqrt(3.0) / d) : 0.0f;
        vtab[p*4+0] = dx * inv; vtab[p*4+1] = dy * inv;
        vtab[p*4+2] = dz * inv; vtab[p*4+3] = 0.0f;
    }
    const float ALPHA = 0.14433756729740643f;   // 1/sqrt(48)
    for (int q = threadIdx.x; q < 2304; q += blockDim.x) {
        float acc = 0.0f;
#pragma unroll
        for (int r = 0; r < 8; r++) acc = fmaf(emb[r], wt[r*2304 + q], acc);
        acc *= (1.0f / 125.0f);
        float val = acc * ((q < 1792) ? ALPHA : (1.0f / 12.0f));
        wbuf[p*2304 + q] = val;
        if (p == 62) {  // center tap: val==0 (EMB(0)=0); fold sc matrices
            if (q < 1024)                   A0[q]        = wsc0[q] * 0.17677669529663687f + val;
            else if (q >= 1536 && q < 1792) A1[q-1536]   = wsc1[q-1536] * 0.25f + val;
        }
    }
}

// ============================================================
// Kernel 2: scatter. Two-pass per block: LDS histogram of 216 regions,
// ONE padded global atomic per (block,region), LDS-cursor placement.
// ============================================================
__global__ __launch_bounds__(256) void scatter_kernel(const int* __restrict__ coords,
        int* __restrict__ vol, int* __restrict__ rcnt_pad, int2* __restrict__ plist) {
    __shared__ int hist[216];
    __shared__ int rbase[216];
    for (int i = threadIdx.x; i < 216; i += 256) hist[i] = 0;
    __syncthreads();
    for (int n = blockIdx.x * 256 + threadIdx.x; n < N_PTS; n += 65536) {
        int x = coords[n*3], y = coords[n*3+1], z = coords[n*3+2];
        vol[(x * GRIDL + y) * GRIDL + z] = n;
        int r = (x >> 5) * 36 + (y >> 5) * 6 + (z >> 5);
        atomicAdd(&hist[r], 1);
    }
    __syncthreads();
    if (threadIdx.x < 216) {
        rbase[threadIdx.x] = atomicAdd(&rcnt_pad[threadIdx.x * 32], hist[threadIdx.x]);
        hist[threadIdx.x] = 0;   // reuse as cursor
    }
    __syncthreads();
    for (int n = blockIdx.x * 256 + threadIdx.x; n < N_PTS; n += 65536) {
        int x = coords[n*3], y = coords[n*3+1], z = coords[n*3+2];
        int r = (x >> 5) * 36 + (y >> 5) * 6 + (z >> 5);
        int j = rbase[r] + atomicAdd(&hist[r], 1);
        if (j < RCAP) plist[r * RCAP + j] = make_int2(n, (x << 16) | (y << 8) | z);
    }
}

// ============================================================
// Kernel 3: enumerate hits. One block per 32^3 region; hits append into
// LDS per-tap lists (LDS atomics), ONE padded global atomic per
// (block,tap) reserves bin space, then coalesced copy-out.
// ============================================================
__global__ __launch_bounds__(256) void enum_kernel(const int* __restrict__ vol,
        const int* __restrict__ rcnt_pad, const int2* __restrict__ plist,
        int* __restrict__ bcnt_pad, int2* __restrict__ bins) {
    int r = blockIdx.x;
    int cnt = min(rcnt_pad[r * 32], RCAP);
    __shared__ int hist[80];
    __shared__ int tbase[80];
    __shared__ int2 stage[80][SCAP];     // 61.4 KB
    for (int i = threadIdx.x; i < 80; i += 256) hist[i] = 0;
    __syncthreads();
    for (int idx = threadIdx.x; idx < cnt; idx += 256) {
        int2 e = plist[r * RCAP + idx];
        int n = e.x, x = e.y >> 16, y = (e.y >> 8) & 255, z = e.y & 255;
        int t = 0;
#pragma unroll
        for (int a = -2; a <= 2; a++)
#pragma unroll
        for (int b = -2; b <= 2; b++)
#pragma unroll
        for (int c = -2; c <= 2; c++) {
            int sq = a*a + b*b + c*c;
            if (sq < 1 || sq > 6) continue;     // dead tap: K==0
            int cx = x + a, cy = y + b, cz = z + c;
            if (((unsigned)cx < 192u) && ((unsigned)cy < 192u) && ((unsigned)cz < 192u)) {
                int nb = vol[(cx * GRIDL + cy) * GRIDL + cz];
                if (nb >= 0) {
                    int j = atomicAdd(&hist[t], 1);
                    if (j < SCAP) stage[t][j] = make_int2(n, nb);
                }
            }
            t++;
        }
    }
    __syncthreads();
    if (threadIdx.x < 80) {
        int c = min(hist[threadIdx.x], SCAP);
        tbase[threadIdx.x] = atomicAdd(&bcnt_pad[TAPS.p[threadIdx.x] * 32], c);
    }
    __syncthreads();
    for (int t = 0; t < 80; t++) {
        int c = min(hist[t], SCAP);
        if (threadIdx.x < c) {
            int slot = tbase[t] + threadIdx.x;
            if (slot < CAP) bins[TAPS.p[t] * CAP + slot] = stage[t][threadIdx.x];
        }
    }
}

// ============================================================
// Kernel 4: out[n] = sc(feats[n])  (fully initializes d_out)
// ============================================================
__global__ __launch_bounds__(256) void sc_self_kernel(const float* __restrict__ feats,
        const float* __restrict__ A0, const float* __restrict__ A1,
        float* __restrict__ out) {
    __shared__ __align__(16) float sA0[1024];
    __shared__ __align__(16) float sA1[256];
    for (int i = threadIdx.x; i < 1024; i += 256) sA0[i] = A0[i];
    if (threadIdx.x < 256) sA1[threadIdx.x] = A1[threadIdx.x];
    __syncthreads();
    int n = blockIdx.x * 256 + threadIdx.x;
    if (n >= N_PTS) return;
    const float4* fr = (const float4*)(feats + (size_t)n * 80);
    float4* orow = (float4*)(out + (size_t)n * 80);
    float f0[32];
#pragma unroll
    for (int j = 0; j < 8; j++) {
        float4 t = fr[j];
        f0[4*j] = t.x; f0[4*j+1] = t.y; f0[4*j+2] = t.z; f0[4*j+3] = t.w;
    }
    float a0[32];
#pragma unroll
    for (int k = 0; k < 32; k++) a0[k] = 0.0f;
#pragma unroll
    for (int i = 0; i < 32; i++) {
        float fv = f0[i];
#pragma unroll
        for (int k4 = 0; k4 < 8; k4++) {
            float4 w = ((const float4*)sA0)[i*8 + k4];
            a0[4*k4]   = fmaf(fv, w.x, a0[4*k4]);
            a0[4*k4+1] = fmaf(fv, w.y, a0[4*k4+1]);
            a0[4*k4+2] = fmaf(fv, w.z, a0[4*k4+2]);
            a0[4*k4+3] = fmaf(fv, w.w, a0[4*k4+3]);
        }
    }
#pragma unroll
    for (int j = 0; j < 8; j++) orow[j] = make_float4(a0[4*j], a0[4*j+1], a0[4*j+2], a0[4*j+3]);
    float f1[48];
#pragma unroll
    for (int j = 0; j < 12; j++) {
        float4 t = fr[8 + j];
        f1[4*j] = t.x; f1[4*j+1] = t.y; f1[4*j+2] = t.z; f1[4*j+3] = t.w;
    }
    float a1[48];
#pragma unroll
    for (int k = 0; k < 48; k++) a1[k] = 0.0f;
#pragma unroll
    for (int i = 0; i < 16; i++) {
        float fm0 = f1[3*i], fm1 = f1[3*i+1], fm2 = f1[3*i+2];
#pragma unroll
        for (int k4 = 0; k4 < 4; k4++) {
            float4 w = ((const float4*)sA1)[i*4 + k4];
            const float* wp = (const float*)&w;
#pragma unroll
            for (int kk = 0; kk < 4; kk++) {
                int k = 4*k4 + kk;
                a1[3*k]   = fmaf(fm0, wp[kk], a1[3*k]);
                a1[3*k+1] = fmaf(fm1, wp[kk], a1[3*k+1]);
                a1[3*k+2] = fmaf(fm2, wp[kk], a1[3*k+2]);
            }
        }
    }
#pragma unroll
    for (int j = 0; j < 12; j++) orow[8+j] = make_float4(a1[4*j], a1[4*j+1], a1[4*j+2], a1[4*j+3]);
}

// ============================================================
// Kernel 5: per-tap bins -> structured 80x80 apply + coalesced atomic flush
// ============================================================
__global__ __launch_bounds__(128) void bin_kernel(const float* __restrict__ feats,
        const float* __restrict__ wbuf, const float* __restrict__ vtab,
        const int* __restrict__ bcnt_pad, const int2* __restrict__ bins,
        float* __restrict__ out) {
    int p = blockIdx.x >> 4;
    int chunk = blockIdx.x & 15;
    int cnt = min(bcnt_pad[p * 32], CAP);
    int start = chunk * 512;
    if (start >= cnt) return;

    __shared__ __align__(16) float sW[2304];
    __shared__ float sv[4];
    __shared__ float ystage[2][64][81];
    __shared__ int   nst[2][64];

    for (int i = threadIdx.x; i < 2304; i += 128) sW[i] = wbuf[p*2304 + i];
    if (threadIdx.x < 4) sv[threadIdx.x] = vtab[p*4 + threadIdx.x];
    __syncthreads();

    int wv = threadIdx.x >> 6, lane = threadIdx.x & 63;
    const float4* sW1 = (const float4*)sW;            // [32][8]
    const float4* sW2 = (const float4*)(sW + 1024);   // [32][4]
    const float4* sW3 = (const float4*)(sW + 1536);   // [16][4]
    const float4* sW4 = (const float4*)(sW + 1792);   // [16][8]
    float v0 = sv[0], v1 = sv[1], v2 = sv[2];

    for (int it = 0; it < 4; it++) {
        int h = start + it * 128 + threadIdx.x;
        bool act = h < cnt;
        int n = -1, nb = 0;
        if (act) { int2 e = bins[p*CAP + h]; n = e.x; nb = e.y; }

        const float4* fr = (const float4*)(feats + (size_t)nb * 80);
        float f0[32], f1[48];
#pragma unroll
        for (int j = 0; j < 8; j++) {
            float4 t = fr[j];
            f0[4*j] = t.x; f0[4*j+1] = t.y; f0[4*j+2] = t.z; f0[4*j+3] = t.w;
        }
#pragma unroll
        for (int j = 0; j < 12; j++) {
            float4 t = fr[8 + j];
            f1[4*j] = t.x; f1[4*j+1] = t.y; f1[4*j+2] = t.z; f1[4*j+3] = t.w;
        }
        float g[16];
#pragma unroll
        for (int i = 0; i < 16; i++)
            g[i] = f1[3*i]*v0 + f1[3*i+1]*v1 + f1[3*i+2]*v2;

        float a0[32], cc[16];
#pragma unroll
        for (int k = 0; k < 32; k++) a0[k] = 0.0f;
#pragma unroll
        for (int k = 0; k < 16; k++) cc[k] = 0.0f;
#pragma unroll
        for (int i = 0; i < 32; i++) {
            float fv = f0[i];
#pragma unroll
            for (int k4 = 0; k4 < 8; k4++) {
                float4 w = sW1[i*8 + k4];
                a0[4*k4]   = fmaf(fv, w.x, a0[4*k4]);
                a0[4*k4+1] = fmaf(fv, w.y, a0[4*k4+1]);
                a0[4*k4+2] = fmaf(fv, w.z, a0[4*k4+2]);
                a0[4*k4+3] = fmaf(fv, w.w, a0[4*k4+3]);
            }
#pragma unroll
            for (int k4 = 0; k4 < 4; k4++) {
                float4 w = sW2[i*4 + k4];
                cc[4*k4]   = fmaf(fv, w.x, cc[4*k4]);
                cc[4*k4+1] = fmaf(fv, w.y, cc[4*k4+1]);
                cc[4*k4+2] = fmaf(fv, w.z, cc[4*k4+2]);
                cc[4*k4+3] = fmaf(fv, w.w, cc[4*k4+3]);
            }
        }
#pragma unroll
        for (int i = 0; i < 16; i++) {
            float gv = g[i];
#pragma unroll
            for (int k4 = 0; k4 < 8; k4++) {
                float4 w = sW4[i*8 + k4];
                a0[4*k4]   = fmaf(gv, w.x, a0[4*k4]);
                a0[4*k4+1] = fmaf(gv, w.y, a0[4*k4+1]);
                a0[4*k4+2] = fmaf(gv, w.z, a0[4*k4+2]);
                a0[4*k4+3] = fmaf(gv, w.w, a0[4*k4+3]);
            }
        }
#pragma unroll
        for (int k = 0; k < 32; k++) ystage[wv][lane][k] = a0[k];

        float a1[48];
#pragma unroll
        for (int k = 0; k < 16; k++) {
            a1[3*k] = v0 * cc[k]; a1[3*k+1] = v1 * cc[k]; a1[3*k+2] = v2 * cc[k];
        }
#pragma unroll
        for (int i = 0; i < 16; i++) {
            float fm0 = f1[3*i], fm1 = f1[3*i+1], fm2 = f1[3*i+2];
#pragma unroll
            for (int k4 = 0; k4 < 4; k4++) {
                float4 w = sW3[i*4 + k4];
                const float* wp = (const float*)&w;
#pragma unroll
                for (int kk = 0; kk < 4; kk++) {
                    int k = 4*k4 + kk;
                    a1[3*k]   = fmaf(fm0, wp[kk], a1[3*k]);
                    a1[3*k+1] = fmaf(fm1, wp[kk], a1[3*k+1]);
                    a1[3*k+2] = fmaf(fm2, wp[kk], a1[3*k+2]);
                }
            }
        }
#pragma unroll
        for (int k = 0; k < 48; k++) ystage[wv][lane][32 + k] = a1[k];
        nst[wv][lane] = act ? n : -1;
        __syncthreads();

        for (int h2 = 0; h2 < 64; h2++) {
            int nn = nst[wv][h2];          // wave-uniform
            if (nn < 0) continue;
            float* orow = out + (size_t)nn * 80;
            unsafeAtomicAdd(orow + lane, ystage[wv][h2][lane]);
            if (lane < 16) unsafeAtomicAdd(orow + 64 + lane, ystage[wv][h2][64 + lane]);
        }
        __syncthreads();
    }
}

extern "C" void kernel_launch(void* const* d_in, const int* in_sizes, int n_in,
                              void* d_out, int out_size, void* d_ws, size_t ws_size,
                              hipStream_t stream) {
    const float* feats = (const float*)d_in[0];
    const float* wt    = (const float*)d_in[1];
    const float* wsc0  = (const float*)d_in[2];
    const float* wsc1  = (const float*)d_in[3];
    const int*   coords= (const int*)d_in[4];
    float* out = (float*)d_out;
    char* ws = (char*)d_ws;

    int*   vol      = (int*)(ws + VOL_OFF);
    int2*  bins     = (int2*)(ws + BINS_OFF);
    int*   bcnt_pad = (int*)(ws + BCNT_OFF);
    int*   rcnt_pad = (int*)(ws + RCNT_OFF);
    int2*  plist    = (int2*)(ws + PLIST_OFF);
    float* wbuf     = (float*)(ws + WBUF_OFF);
    float* vtab     = (float*)(ws + VTAB_OFF);
    float* A0       = (float*)(ws + A0_OFF);
    float* A1       = (float*)(ws + A1_OFF);

    hipMemsetAsync(vol, 0xFF, VOL_BYTES, stream);                 // -1 everywhere
    hipMemsetAsync(bcnt_pad, 0, 16000 + 27648, stream);           // bcnt_pad + rcnt_pad

    prep_kernel<<<125, 256, 0, stream>>>(wt, wsc0, wsc1, wbuf, vtab, A0, A1);
    scatter_kernel<<<256, 256, 0, stream>>>(coords, vol, rcnt_pad, plist);
    enum_kernel<<<NREG, 256, 0, stream>>>(vol, rcnt_pad, plist, bcnt_pad, bins);
    sc_self_kernel<<<(N_PTS + 255) / 256, 256, 0, stream>>>(feats, A0, A1, out);
    bin_kernel<<<125 * 16, 128, 0, stream>>>(feats, wbuf, vtab, bcnt_pad, bins, out);
}